// Round 1
// baseline (191.698 us; speedup 1.0000x reference)
//
#include <hip/hip_runtime.h>

// Problem constants
#define RCH 64        // residual channels (x, outputs)
#define DCH 64        // dilated/gated channels
#define SCH 128       // skip channels
#define DIL 8
#define NB 32
#define TLEN 16384
#define TT 128        // time tile per block
#define HALO 8        // causal halo = (K-1)*DIL
#define PITCH 72      // LDS row pitch in bf16 elems (144B: 16B-aligned, breaks 128B bank stride)

typedef __attribute__((ext_vector_type(8))) short bf16x8;   // 8 bf16 = 4 VGPRs (MFMA A/B frag)
typedef __attribute__((ext_vector_type(4))) short short4v;
typedef __attribute__((ext_vector_type(8))) short short8v;
typedef __attribute__((ext_vector_type(4))) float f32x4;

__device__ __forceinline__ short f32_bf16(float f) {
    union { float f; unsigned int u; } v; v.f = f;
    unsigned int u = v.u;
    u += 0x7FFFu + ((u >> 16) & 1u);   // round-to-nearest-even
    return (short)(u >> 16);
}

__device__ __forceinline__ f32x4 mfma16(bf16x8 a, bf16x8 b, f32x4 c) {
    return __builtin_amdgcn_mfma_f32_16x16x32_bf16(a, b, c, 0, 0, 0);
}

// ---------------------------------------------------------------------------
// ws layout: 56 fragments, each = 64 lanes * 8 bf16 (lane-major, 16B/lane).
//   frags  0..15 : w_gate   [dct(4)][tap(2)][ksub(2)]
//   frags 16..31 : w_filter [dct(4)][tap(2)][ksub(2)]
//   frags 32..47 : w_skip   [sct(8)][ksub(2)]
//   frags 48..55 : w_out    [rct(4)][ksub(2)]
// A-frag layout for mfma_f32_16x16x32_bf16: lane l holds W[m=l&15][k=8*(l>>4)+e]
// Total: 56*512*2B = 57344 bytes of d_ws.
// ---------------------------------------------------------------------------
__global__ void prep_weights(const float* __restrict__ wg, const float* __restrict__ wf,
                             const float* __restrict__ wsk, const float* __restrict__ wo,
                             short* __restrict__ ws)
{
    int gid = blockIdx.x * blockDim.x + threadIdx.x;
    if (gid >= 56 * 64) return;
    int frag = gid >> 6;
    int lane = gid & 63;
    int row = lane & 15;
    int kb = (lane >> 4) * 8;
    short o[8];
    if (frag < 32) {
        const float* w = (frag < 16) ? wg : wf;
        int fl = frag & 15;
        int dct = fl >> 2, tap = (fl >> 1) & 1, ks = fl & 1;
        int dc = dct * 16 + row;
        #pragma unroll
        for (int e = 0; e < 8; ++e) {
            int rc = ks * 32 + kb + e;
            o[e] = f32_bf16(w[(dc * RCH + rc) * 2 + tap]);
        }
    } else if (frag < 48) {
        int fl = frag - 32;
        int sct = fl >> 1, ks = fl & 1;
        int sc = sct * 16 + row;
        #pragma unroll
        for (int e = 0; e < 8; ++e) o[e] = f32_bf16(wsk[sc * DCH + ks * 32 + kb + e]);
    } else {
        int fl = frag - 48;
        int rct = fl >> 1, ks = fl & 1;
        int rc = rct * 16 + row;
        #pragma unroll
        for (int e = 0; e < 8; ++e) o[e] = f32_bf16(wo[rc * DCH + ks * 32 + kb + e]);
    }
    short8v v;
    #pragma unroll
    for (int e = 0; e < 8; ++e) v[e] = o[e];
    *(short8v*)(ws + (size_t)frag * 512 + lane * 8) = v;
}

// ---------------------------------------------------------------------------
// Main fused kernel: one block = one (batch, 128-t tile). 4 waves, each owns a
// 32-t slice (2 16x16 t-tiles) and all 64 output channels.
// Phase 1: conv via MFMA (tap0 = LDS row offset -8), gate epilogue -> cT.
// Phase 2: skip/out 1x1 via MFMA from cT, fp32 residual re-read from global.
// ---------------------------------------------------------------------------
__global__ __launch_bounds__(256, 2) void fused_block(
    const float* __restrict__ x,
    const short* __restrict__ ws,
    const float* __restrict__ b_gate, const float* __restrict__ b_filter,
    const float* __restrict__ b_skip, const float* __restrict__ b_out,
    float* __restrict__ out, float* __restrict__ skip)
{
    __shared__ __align__(16) short xT[TT + HALO][PITCH];  // bf16 x^T tile (with halo)
    __shared__ __align__(16) short cT[TT][PITCH];         // bf16 concat^T tile

    const int bidT = blockIdx.x & 127;          // T/TT = 128 tiles
    const int b    = blockIdx.x >> 7;
    const int t0   = bidT * TT;
    const int tid  = threadIdx.x;

    // ---- stage x tile: fp32 global -> bf16 LDS, transposed ----
    {
        int r   = tid & 127;                    // local row, t = t0 - 8 + r
        int rcb = (tid >> 7) * 32;              // rc half
        int t   = t0 - HALO + r;
        const float* xb = x + (size_t)b * RCH * TLEN + t;
        bool valid = (t >= 0);
        #pragma unroll
        for (int i = 0; i < 8; ++i) {
            short4v pk;
            #pragma unroll
            for (int j = 0; j < 4; ++j) {
                float v = valid ? xb[(size_t)(rcb + i * 4 + j) * TLEN] : 0.f;
                pk[j] = f32_bf16(v);
            }
            *(short4v*)&xT[r][rcb + i * 4] = pk;
        }
        if (tid < 16) {                         // rows 128..135
            int r2   = 128 + (tid & 7);
            int rcb2 = (tid >> 3) * 32;
            const float* xb2 = x + (size_t)b * RCH * TLEN + (t0 - HALO + r2);
            #pragma unroll
            for (int i = 0; i < 8; ++i) {
                short4v pk;
                #pragma unroll
                for (int j = 0; j < 4; ++j)
                    pk[j] = f32_bf16(xb2[(size_t)(rcb2 + i * 4 + j) * TLEN]);
                *(short4v*)&xT[r2][rcb2 + i * 4] = pk;
            }
        }
    }
    __syncthreads();

    const int lane  = tid & 63;
    const int w     = tid >> 6;
    const int row16 = lane & 15;   // n (= t) within tile
    const int kgrp  = lane >> 4;   // k-group
    const int lt    = w * 32;      // this wave's local-t base

    // ---- conv B-frags: X cur and X prev (t-8) ----
    bf16x8 xc[2][2], xp[2][2];     // [t-tile][ksub]
    #pragma unroll
    for (int tt = 0; tt < 2; ++tt) {
        #pragma unroll
        for (int ks = 0; ks < 2; ++ks) {
            int rowc = HALO + lt + tt * 16 + row16;
            int col  = ks * 32 + kgrp * 8;
            xc[tt][ks] = *(const bf16x8*)&xT[rowc][col];
            xp[tt][ks] = *(const bf16x8*)&xT[rowc - DIL][col];
        }
    }

    // ---- phase 1: conv + sigmoid*tanh -> cT ----
    #pragma unroll
    for (int dct = 0; dct < 4; ++dct) {
        bf16x8 ag[2][2], af[2][2];  // [tap][ksub]
        #pragma unroll
        for (int tap = 0; tap < 2; ++tap) {
            #pragma unroll
            for (int ks = 0; ks < 2; ++ks) {
                ag[tap][ks] = *(const bf16x8*)(ws + (size_t)(dct * 4 + tap * 2 + ks) * 512 + lane * 8);
                af[tap][ks] = *(const bf16x8*)(ws + (size_t)(16 + dct * 4 + tap * 2 + ks) * 512 + lane * 8);
            }
        }
        f32x4 gg[2] = {{0.f,0.f,0.f,0.f},{0.f,0.f,0.f,0.f}};
        f32x4 ff[2] = {{0.f,0.f,0.f,0.f},{0.f,0.f,0.f,0.f}};
        #pragma unroll
        for (int tt = 0; tt < 2; ++tt) {
            #pragma unroll
            for (int ks = 0; ks < 2; ++ks) {
                gg[tt] = mfma16(ag[0][ks], xp[tt][ks], gg[tt]);
                gg[tt] = mfma16(ag[1][ks], xc[tt][ks], gg[tt]);
                ff[tt] = mfma16(af[0][ks], xp[tt][ks], ff[tt]);
                ff[tt] = mfma16(af[1][ks], xc[tt][ks], ff[tt]);
            }
        }
        int dcb = dct * 16 + kgrp * 4;
        f32x4 bg = *(const f32x4*)(b_gate + dcb);
        f32x4 bf = *(const f32x4*)(b_filter + dcb);
        #pragma unroll
        for (int tt = 0; tt < 2; ++tt) {
            short4v pk;
            #pragma unroll
            for (int r = 0; r < 4; ++r) {
                float gp = gg[tt][r] + bg[r];
                float fp = ff[tt][r] + bf[r];
                float sg = __builtin_amdgcn_rcpf(1.f + __expf(-gp));
                float e2 = __expf(2.f * fp);
                float th = 1.f - 2.f * __builtin_amdgcn_rcpf(e2 + 1.f);
                pk[r] = f32_bf16(sg * th);
            }
            *(short4v*)&cT[lt + tt * 16 + row16][dcb] = pk;
        }
    }
    // no __syncthreads needed: each wave reads back only its own 32 cT rows

    // ---- phase 2 B-frags from cT ----
    bf16x8 cb[2][2];
    #pragma unroll
    for (int tt = 0; tt < 2; ++tt) {
        #pragma unroll
        for (int ks = 0; ks < 2; ++ks)
            cb[tt][ks] = *(const bf16x8*)&cT[lt + tt * 16 + row16][ks * 32 + kgrp * 8];
    }

    const int t_ = t0 + lt + row16;
    const size_t outbase  = (size_t)b * RCH * TLEN;
    const size_t skipbase = (size_t)b * SCH * TLEN;

    // skip = Wsk @ concat + b_skip
    #pragma unroll
    for (int sct = 0; sct < 8; ++sct) {
        bf16x8 a0 = *(const bf16x8*)(ws + (size_t)(32 + sct * 2 + 0) * 512 + lane * 8);
        bf16x8 a1 = *(const bf16x8*)(ws + (size_t)(32 + sct * 2 + 1) * 512 + lane * 8);
        f32x4 acc0 = {0.f,0.f,0.f,0.f}, acc1 = {0.f,0.f,0.f,0.f};
        acc0 = mfma16(a0, cb[0][0], acc0); acc0 = mfma16(a1, cb[0][1], acc0);
        acc1 = mfma16(a0, cb[1][0], acc1); acc1 = mfma16(a1, cb[1][1], acc1);
        int scb = sct * 16 + kgrp * 4;
        f32x4 bs = *(const f32x4*)(b_skip + scb);
        #pragma unroll
        for (int r = 0; r < 4; ++r) {
            skip[skipbase + (size_t)(scb + r) * TLEN + t_]      = acc0[r] + bs[r];
            skip[skipbase + (size_t)(scb + r) * TLEN + t_ + 16] = acc1[r] + bs[r];
        }
    }

    // out = Wout @ concat + b_out + x  (fp32 residual)
    #pragma unroll
    for (int rct = 0; rct < 4; ++rct) {
        bf16x8 a0 = *(const bf16x8*)(ws + (size_t)(48 + rct * 2 + 0) * 512 + lane * 8);
        bf16x8 a1 = *(const bf16x8*)(ws + (size_t)(48 + rct * 2 + 1) * 512 + lane * 8);
        f32x4 acc0 = {0.f,0.f,0.f,0.f}, acc1 = {0.f,0.f,0.f,0.f};
        acc0 = mfma16(a0, cb[0][0], acc0); acc0 = mfma16(a1, cb[0][1], acc0);
        acc1 = mfma16(a0, cb[1][0], acc1); acc1 = mfma16(a1, cb[1][1], acc1);
        int rcb = rct * 16 + kgrp * 4;
        f32x4 bo = *(const f32x4*)(b_out + rcb);
        #pragma unroll
        for (int r = 0; r < 4; ++r) {
            size_t i0 = outbase + (size_t)(rcb + r) * TLEN + t_;
            out[i0]      = acc0[r] + bo[r] + x[i0];
            out[i0 + 16] = acc1[r] + bo[r] + x[i0 + 16];
        }
    }
}

extern "C" void kernel_launch(void* const* d_in, const int* in_sizes, int n_in,
                              void* d_out, int out_size, void* d_ws, size_t ws_size,
                              hipStream_t stream) {
    (void)in_sizes; (void)n_in; (void)out_size; (void)ws_size;
    const float* x        = (const float*)d_in[0];
    const float* w_gate   = (const float*)d_in[1];
    const float* b_gate   = (const float*)d_in[2];
    const float* w_filter = (const float*)d_in[3];
    const float* b_filter = (const float*)d_in[4];
    const float* w_skip   = (const float*)d_in[5];
    const float* b_skip   = (const float*)d_in[6];
    const float* w_out    = (const float*)d_in[7];
    const float* b_out    = (const float*)d_in[8];
    float* out  = (float*)d_out;
    float* skip = out + (size_t)NB * RCH * TLEN;
    short* ws   = (short*)d_ws;   // needs 57344 bytes

    prep_weights<<<14, 256, 0, stream>>>(w_gate, w_filter, w_skip, w_out, ws);
    fused_block<<<NB * (TLEN / TT), 256, 0, stream>>>(
        x, ws, b_gate, b_filter, b_skip, b_out, out, skip);
}